// Round 9
// baseline (444.832 us; speedup 1.0000x reference)
//
#include <hip/hip_runtime.h>

#define B_  32
#define T_  256
#define F_  64
#define C_  16
#define CO_ 16
#define P_  64
#define S_  32
#define K_  4
#define FC_ 1024   // F*C
#define OUTC 96
#define TT  4      // t-tile per block (v9: halved for 3 blocks/CU)
#define NS  10     // TT + 6 halo slices (dilation*(K-1) = 6)

// v9 = v6 structure at TT=4: LDS 74 -> 49 KB => 3 blocks/CU (24 waves/CU).
// Theory: all pipes individually unsaturated (VALU ~45us, LDS ~40-80us,
// HBM ~50us vs kernel ~105us); v3/v5/v6/v8 falsified barriers / GEMM /
// LDS-issue as bottlenecks. Remaining: phase-overlap limited by 2 resident
// blocks. +50% TLP, halved phase granularity. Proven pieces unchanged:
// bulk xs staging, register-resident conv/px, monolithic 24KB row dumps,
// lgkm-only barriers, identical accumulation order.
//  LDS map (float lds[12544], 49 KB):
//    [0..10240)     xs: 10 x slices (dead after conv)
//    [10240..12288) part: phase-1 partials (dead after 1b)
//    [12288..12544) pv: relu'd point rows (live to the end)
//    dump staging: st[i] = lds + i*6144, i=0,1 (aliases dead xs/part)
__global__ __launch_bounds__(512, 6) void tpc_fused(
    const float* __restrict__ x, const float* __restrict__ stat,
    const float* __restrict__ cw, const float* __restrict__ cb,
    const float* __restrict__ Wp, const float* __restrict__ bp,
    float* __restrict__ out)
{
    __shared__ __align__(16) float lds[12544];   // 49 KB
    float* xs   = lds;            // [0..10240)
    float* part = lds + 10240;    // [10240..12288)
    float* pv   = lds + 12288;    // [12288..12544)

    int tid = threadIdx.x;
    int blk = blockIdx.x;      // 0..2047
    int b  = blk >> 6;
    int t0 = (blk & 63) * TT;

    // ---- stage x[t0-6 .. t0+TT-1, :, :] into LDS (zero left pad) ----
    #pragma unroll
    for (int it = 0; it < 5; ++it) {
        int v = it * 512 + tid;            // float4 id, NS*256 = 2560 total
        int slice = v >> 8;
        int pos   = v & 255;
        int tg = t0 - 6 + slice;
        float4 val = make_float4(0.f, 0.f, 0.f, 0.f);
        if (tg >= 0)
            val = *(const float4*)(x + ((size_t)(b * T_ + tg)) * FC_ + pos * 4);
        *(float4*)(xs + slice * FC_ + pos * 4) = val;
    }
    __syncthreads();

    // ---- phase 1: point GEMM partials; wave = one 128-wide k slice ----
    {
        int p  = tid & 63;
        int ks = tid >> 6;                 // 0..7
        float acc[TT];
        #pragma unroll
        for (int r = 0; r < TT; ++r) acc[r] = 0.f;
        int k0base = ks * 128;
        for (int kk = 0; kk < 128; kk += 4) {
            int k0 = k0base + kk;
            float w0 = Wp[(size_t)(k0 + 0) * P_ + p];
            float w1 = Wp[(size_t)(k0 + 1) * P_ + p];
            float w2 = Wp[(size_t)(k0 + 2) * P_ + p];
            float w3 = Wp[(size_t)(k0 + 3) * P_ + p];
            #pragma unroll
            for (int r = 0; r < TT; ++r) {
                float4 xv = *(const float4*)(xs + (6 + r) * FC_ + k0);
                acc[r] += xv.x * w0 + xv.y * w1 + xv.z * w2 + xv.w * w3;
            }
        }
        #pragma unroll
        for (int r = 0; r < TT; ++r)
            part[(ks * TT + r) * P_ + p] = acc[r];
    }
    __syncthreads();

    int p  = tid & 63;
    int co = tid & 15;
    int fh = tid >> 4;                     // 0..31 (local f within half)
    int fg = tid >> 6;                     // 0..7

    // ---- phase 1b: reduce + bias + static; relu -> pv (waves 0..3) ----
    {
        int r = tid >> 6;                  // 0..7; rows 0..3 active
        if (r < TT) {
            float s = bp[p];
            const float* wst = Wp + (size_t)FC_ * P_;
            #pragma unroll 8
            for (int si = 0; si < S_; ++si)
                s += stat[b * S_ + si] * wst[si * P_ + p];
            #pragma unroll
            for (int ks = 0; ks < 8; ++ks)
                s += part[(ks * TT + r) * P_ + p];
            pv[r * P_ + p] = fmaxf(s, 0.f);
        }
    }

    // ---- conv + x passthrough -> registers (xs reads, no barriers) ----
    float cv[2][TT], px[2][TT];
    #pragma unroll
    for (int half = 0; half < 2; ++half) {
        int f = half * 32 + fh;
        float w[64];
        const float4* wg = (const float4*)(cw + ((size_t)(f * CO_ + co)) * (C_ * K_));
        #pragma unroll
        for (int j = 0; j < 16; ++j) {
            float4 t4 = wg[j];
            w[4 * j + 0] = t4.x; w[4 * j + 1] = t4.y;
            w[4 * j + 2] = t4.z; w[4 * j + 3] = t4.w;
        }
        float bias = cb[f * CO_ + co];
        #pragma unroll
        for (int tl = 0; tl < TT; ++tl) {
            float temp = bias;
            #pragma unroll
            for (int k = 0; k < K_; ++k) {
                const float* sp = xs + (tl + 2 * k) * FC_ + f * C_;
                #pragma unroll
                for (int c4 = 0; c4 < 4; ++c4) {
                    float4 xv = *(const float4*)(sp + c4 * 4);
                    temp += xv.x * w[(c4 * 4 + 0) * 4 + k];
                    temp += xv.y * w[(c4 * 4 + 1) * 4 + k];
                    temp += xv.z * w[(c4 * 4 + 2) * 4 + k];
                    temp += xv.w * w[(c4 * 4 + 3) * 4 + k];
                }
            }
            cv[half][tl] = fmaxf(temp, 0.f);
            px[half][tl] = fmaxf(xs[(tl + 6) * FC_ + f * C_ + co], 0.f);
        }
    }
    __syncthreads();   // all xs/part reads drained (both dead); pv visible

    // hoist pv rows for this thread's p
    float pvr[TT];
    #pragma unroll
    for (int tl = 0; tl < TT; ++tl)
        pvr[tl] = pv[tl * P_ + p];

    // ---- pure dump loop: 4 iterations, 24 KB monolithic stores ----
    for (int tl = 0; tl < TT; ++tl) {
        float* st = lds + (tl & 1) * 6144;   // aliases dead xs/part
        // stage full t-row [f=0..63][96] from registers
        st[fh * OUTC + co]               = px[0][tl];
        st[fh * OUTC + 16 + co]          = cv[0][tl];
        st[(fh + 32) * OUTC + co]        = px[1][tl];
        st[(fh + 32) * OUTC + 16 + co]   = cv[1][tl];
        float pvv = pvr[tl];
        #pragma unroll
        for (int fo = 0; fo < 8; ++fo)
            st[(fo * 8 + fg) * OUTC + 32 + p] = pvv;

        // single lgkm-only barrier (double buffer; prev readers of this buffer
        // drained their reads at the previous barrier; stores never drained)
        asm volatile("s_waitcnt lgkmcnt(0)" ::: "memory");
        __builtin_amdgcn_sched_barrier(0);
        __builtin_amdgcn_s_barrier();
        __builtin_amdgcn_sched_barrier(0);

        // dump 24 KB contiguous (one full t row, full 128B lines)
        const float4* src = (const float4*)st;
        float4* dst = (float4*)(out + ((size_t)(b * T_ + t0 + tl)) * F_ * OUTC);
        dst[tid]        = src[tid];
        dst[512 + tid]  = src[512 + tid];
        dst[1024 + tid] = src[1024 + tid];
    }
}

extern "C" void kernel_launch(void* const* d_in, const int* in_sizes, int n_in,
                              void* d_out, int out_size, void* d_ws, size_t ws_size,
                              hipStream_t stream) {
    const float* x    = (const float*)d_in[0];
    const float* stat = (const float*)d_in[1];
    const float* cw   = (const float*)d_in[2];
    const float* cb   = (const float*)d_in[3];
    const float* Wp   = (const float*)d_in[4];
    const float* bp   = (const float*)d_in[5];
    float* out = (float*)d_out;

    tpc_fused<<<2048, 512, 0, stream>>>(x, stat, cw, cb, Wp, bp, out);
}

// Round 10
// 280.037 us; speedup vs baseline: 1.5885x; 1.5885x over previous
//
#include <hip/hip_runtime.h>

#define B_  32
#define T_  256
#define F_  64
#define C_  16
#define CO_ 16
#define P_  64
#define S_  32
#define K_  4
#define FC_ 1024   // F*C
#define OUTC 96
#define TT  8      // t-tile per block
#define NS  14     // TT + 6 halo slices (dilation*(K-1) = 6)

// v10: wave-autonomous dump. Ledger: monolithic full-line stores mandatory
// (v2); bulk xs staging mandatory (v4); GEMM off critical path (v5); barrier
// TYPE immaterial (v3); LDS-issue not the limit (v8); VGPR squeeze fatal (v9).
// Model: kernel ~= VALU(35us)+LDS(50us)+HBM(40us) SUM because 8-wave barrier
// lockstep + in-phase resident blocks prevent pipe overlap. Fix: stage cv/px
// for ALL 8 rows once (64KB st over dead xs+part), one final barrier, then
// each wave dumps its own t-row with NO synchronization -- waves drift, pipes
// stay co-fed. Barriers 11 -> 4. GEMM/conv/1b identical to v6 (same absmax).
__global__ __launch_bounds__(512, 4) void tpc_fused(
    const float* __restrict__ x, const float* __restrict__ stat,
    const float* __restrict__ cw, const float* __restrict__ cb,
    const float* __restrict__ Wp, const float* __restrict__ bp,
    float* __restrict__ out)
{
    __shared__ __align__(16) float lds[18944];   // 74 KB total
    float* xs   = lds;            // [0..14336)  x slices (dead after conv)
    float* part = lds + 14336;    // [14336..18432) phase-1 partials (dead after 1b)
    float* pv   = lds + 18432;    // [18432..18944) relu'd point rows (live)
    float* st   = lds;            // [0..16384) cv/px staging, aliases xs+part

    int tid = threadIdx.x;
    int blk = blockIdx.x;      // 0..1023
    int b  = blk >> 5;
    int t0 = (blk & 31) * TT;

    // ---- stage x[t0-6 .. t0+TT-1, :, :] into LDS (zero left pad) ----
    #pragma unroll
    for (int it = 0; it < 7; ++it) {
        int v = it * 512 + tid;            // float4 id, NS*256 = 3584 total
        int slice = v >> 8;
        int pos   = v & 255;
        int tg = t0 - 6 + slice;
        float4 val = make_float4(0.f, 0.f, 0.f, 0.f);
        if (tg >= 0)
            val = *(const float4*)(x + ((size_t)(b * T_ + tg)) * FC_ + pos * 4);
        *(float4*)(xs + slice * FC_ + pos * 4) = val;
    }
    __syncthreads();                                   // barrier A

    // ---- phase 1: point GEMM partials; wave = one 128-wide k slice ----
    {
        int p  = tid & 63;
        int ks = tid >> 6;                 // 0..7
        float acc[TT];
        #pragma unroll
        for (int r = 0; r < TT; ++r) acc[r] = 0.f;
        int k0base = ks * 128;
        for (int kk = 0; kk < 128; kk += 4) {
            int k0 = k0base + kk;
            float w0 = Wp[(size_t)(k0 + 0) * P_ + p];
            float w1 = Wp[(size_t)(k0 + 1) * P_ + p];
            float w2 = Wp[(size_t)(k0 + 2) * P_ + p];
            float w3 = Wp[(size_t)(k0 + 3) * P_ + p];
            #pragma unroll
            for (int r = 0; r < TT; ++r) {
                float4 xv = *(const float4*)(xs + (6 + r) * FC_ + k0);
                acc[r] += xv.x * w0 + xv.y * w1 + xv.z * w2 + xv.w * w3;
            }
        }
        #pragma unroll
        for (int r = 0; r < TT; ++r)
            part[(ks * TT + r) * P_ + p] = acc[r];
    }
    __syncthreads();                                   // barrier B

    int p  = tid & 63;
    int co = tid & 15;
    int fh = tid >> 4;                     // 0..31 (local f within half)

    // ---- phase 1b: reduce + bias + static; relu -> pv ----
    {
        int r = tid >> 6;                  // row 0..7
        float s = bp[p];
        const float* wst = Wp + (size_t)FC_ * P_;
        #pragma unroll 8
        for (int si = 0; si < S_; ++si)
            s += stat[b * S_ + si] * wst[si * P_ + p];
        #pragma unroll
        for (int ks = 0; ks < 8; ++ks)
            s += part[(ks * TT + r) * P_ + p];
        pv[r * P_ + p] = fmaxf(s, 0.f);
    }

    // ---- conv + x passthrough -> registers (v6 verbatim) ----
    float cv[2][TT], px[2][TT];
    #pragma unroll
    for (int half = 0; half < 2; ++half) {
        int f = half * 32 + fh;
        float w[64];
        const float4* wg = (const float4*)(cw + ((size_t)(f * CO_ + co)) * (C_ * K_));
        #pragma unroll
        for (int j = 0; j < 16; ++j) {
            float4 t4 = wg[j];
            w[4 * j + 0] = t4.x; w[4 * j + 1] = t4.y;
            w[4 * j + 2] = t4.z; w[4 * j + 3] = t4.w;
        }
        float bias = cb[f * CO_ + co];
        #pragma unroll
        for (int tl = 0; tl < TT; ++tl) {
            float temp = bias;
            #pragma unroll
            for (int k = 0; k < K_; ++k) {
                const float* sp = xs + (tl + 2 * k) * FC_ + f * C_;
                #pragma unroll
                for (int c4 = 0; c4 < 4; ++c4) {
                    float4 xv = *(const float4*)(sp + c4 * 4);
                    temp += xv.x * w[(c4 * 4 + 0) * 4 + k];
                    temp += xv.y * w[(c4 * 4 + 1) * 4 + k];
                    temp += xv.z * w[(c4 * 4 + 2) * 4 + k];
                    temp += xv.w * w[(c4 * 4 + 3) * 4 + k];
                }
            }
            cv[half][tl] = fmaxf(temp, 0.f);
            px[half][tl] = fmaxf(xs[(tl + 6) * FC_ + f * C_ + co], 0.f);
        }
    }
    // barrier C: all xs/part reads drained (both dead); pv visible
    asm volatile("s_waitcnt lgkmcnt(0)" ::: "memory");
    __builtin_amdgcn_sched_barrier(0);
    __builtin_amdgcn_s_barrier();
    __builtin_amdgcn_sched_barrier(0);

    // ---- stage cv/px for ALL 8 rows: st[row][f][32] = [px | cv] ----
    #pragma unroll
    for (int half = 0; half < 2; ++half) {
        int f = half * 32 + fh;
        #pragma unroll
        for (int tl = 0; tl < TT; ++tl) {
            st[tl * 2048 + f * 32 + co]      = px[half][tl];
            st[tl * 2048 + f * 32 + 16 + co] = cv[half][tl];
        }
    }
    // barrier D: staging visible
    asm volatile("s_waitcnt lgkmcnt(0)" ::: "memory");
    __builtin_amdgcn_sched_barrier(0);
    __builtin_amdgcn_s_barrier();
    __builtin_amdgcn_sched_barrier(0);

    // ---- wave-autonomous dump: wave wid owns row t0+wid, NO barriers ----
    {
        int wid  = tid >> 6;               // 0..7
        int lane = tid & 63;
        float4* dst = (float4*)(out + ((size_t)(b * T_ + t0 + wid)) * F_ * OUTC);
        #pragma unroll
        for (int j = 0; j < 24; ++j) {
            unsigned q   = j * 64 + lane;  // float4 slot in the 1536-slot row
            unsigned f   = q / 24;
            unsigned qw4 = q - f * 24;     // 0..23
            // source: qw4<8 -> st row; else pv row (both LDS: single read)
            int off = (qw4 < 8)
                ? (wid * 2048 + (int)(f * 32 + qw4 * 4))
                : (18432 + wid * 64 + (int)((qw4 - 8) * 4));
            float4 val = *(const float4*)(lds + off);
            dst[q] = val;                  // contiguous 1KB/wave full lines
        }
    }
}

extern "C" void kernel_launch(void* const* d_in, const int* in_sizes, int n_in,
                              void* d_out, int out_size, void* d_ws, size_t ws_size,
                              hipStream_t stream) {
    const float* x    = (const float*)d_in[0];
    const float* stat = (const float*)d_in[1];
    const float* cw   = (const float*)d_in[2];
    const float* cb   = (const float*)d_in[3];
    const float* Wp   = (const float*)d_in[4];
    const float* bp   = (const float*)d_in[5];
    float* out = (float*)d_out;

    tpc_fused<<<1024, 512, 0, stream>>>(x, stat, cw, cb, Wp, bp, out);
}